// Round 1
// baseline (563.163 us; speedup 1.0000x reference)
//
#include <hip/hip_runtime.h>
#include <math.h>

#define BB 2
#define NN 2048
#define DD 256
#define HH 8

// ---------------------------------------------------------------------------
// K1: fused QKV projection.  Q/K/V[n, o] = sum_d X[n,d] * W[o,d] + b[o]
// grid (64, 4, 3): x = 64-row tile, y = 64-col tile, z = which matrix
// ---------------------------------------------------------------------------
__global__ __launch_bounds__(256) void qkv_gemm(
    const float* __restrict__ X,
    const float* __restrict__ Wq, const float* __restrict__ Wk, const float* __restrict__ Wv,
    const float* __restrict__ bq, const float* __restrict__ bk, const float* __restrict__ bv,
    float* __restrict__ Q, float* __restrict__ Kd, float* __restrict__ Vd)
{
    const int tid = threadIdx.x;
    const int z = blockIdx.z;
    const float* Wm = (z == 0) ? Wq : (z == 1) ? Wk : Wv;
    const float* bm = (z == 0) ? bq : (z == 1) ? bk : bv;
    float* Om       = (z == 0) ? Q  : (z == 1) ? Kd : Vd;

    const int n0 = blockIdx.x * 64;
    const int c0 = blockIdx.y * 64;

    __shared__ float As[32][68];   // [k][m], pad 68 keeps 16B alignment + bank spread
    __shared__ float Bs[32][68];   // [k][o]

    const int ty = tid >> 4;   // 0..15
    const int tx = tid & 15;   // 0..15

    float acc[4][4];
#pragma unroll
    for (int i = 0; i < 4; ++i)
#pragma unroll
        for (int j = 0; j < 4; ++j) acc[i][j] = 0.f;

    for (int k0 = 0; k0 < DD; k0 += 32) {
        __syncthreads();
#pragma unroll
        for (int u = 0; u < 2; ++u) {
            int i   = tid * 2 + u;       // 0..511
            int row = i >> 3;            // 0..63
            int cc  = (i & 7) << 2;      // 0,4,..,28
            float4 xv = *(const float4*)(X  + (size_t)(n0 + row) * DD + k0 + cc);
            As[cc + 0][row] = xv.x;
            As[cc + 1][row] = xv.y;
            As[cc + 2][row] = xv.z;
            As[cc + 3][row] = xv.w;
            float4 wv = *(const float4*)(Wm + (size_t)(c0 + row) * DD + k0 + cc);
            Bs[cc + 0][row] = wv.x;
            Bs[cc + 1][row] = wv.y;
            Bs[cc + 2][row] = wv.z;
            Bs[cc + 3][row] = wv.w;
        }
        __syncthreads();
#pragma unroll
        for (int kk = 0; kk < 32; ++kk) {
            float4 a = *(const float4*)&As[kk][ty * 4];
            float4 b = *(const float4*)&Bs[kk][tx * 4];
            const float av[4] = {a.x, a.y, a.z, a.w};
            const float bw[4] = {b.x, b.y, b.z, b.w};
#pragma unroll
            for (int i = 0; i < 4; ++i)
#pragma unroll
                for (int j = 0; j < 4; ++j)
                    acc[i][j] += av[i] * bw[j];
        }
    }

    float bias[4];
#pragma unroll
    for (int j = 0; j < 4; ++j) bias[j] = bm[c0 + tx * 4 + j];
#pragma unroll
    for (int i = 0; i < 4; ++i) {
        float4 o;
        o.x = acc[i][0] + bias[0];
        o.y = acc[i][1] + bias[1];
        o.z = acc[i][2] + bias[2];
        o.w = acc[i][3] + bias[3];
        *(float4*)(Om + (size_t)(n0 + ty * 4 + i) * DD + c0 + tx * 4) = o;
    }
}

// ---------------------------------------------------------------------------
// K2: phase attention.  One block = 64 query rows of one (b,h); each of the
// 4 waves handles a 512-key chunk with one row per lane; K/V loads are
// wave-uniform (scalar path).  Partials combined in LDS.
//   w = 0.5*(1 + re/sqrt(re^2+im^2)) / (sqrt(32)+1e-6);  softmax w/o max-sub.
// ---------------------------------------------------------------------------
__global__ __launch_bounds__(256) void attn_kernel(
    const float* __restrict__ Q, const float* __restrict__ K, const float* __restrict__ V,
    float* __restrict__ outp)
{
    const int tid    = threadIdx.x;
    const int wave   = tid >> 6;     // key chunk 0..3
    const int lane   = tid & 63;
    const int rowblk = blockIdx.x;   // 0..511
    const int bh     = rowblk >> 5;  // 0..15
    const int ntile  = rowblk & 31;
    const int b = bh >> 3, h = bh & 7;
    const int n = ntile * 64 + lane;

    const float* qp = Q + (size_t)(b * NN + n) * DD + h * 32;
    float4 qv[8];
#pragma unroll
    for (int p = 0; p < 8; ++p) qv[p] = *(const float4*)(qp + p * 4);

    float4 av[8];
#pragma unroll
    for (int p = 0; p < 8; ++p) av[p] = make_float4(0.f, 0.f, 0.f, 0.f);
    float denom = 0.f;

    int base0 = (b * NN + wave * 512) * DD + h * 32;
    base0 = __builtin_amdgcn_readfirstlane(base0);   // force scalar K/V addressing
    const float* kbase = K + base0;
    const float* vbase = V + base0;

    const float inv_s = 1.0f / (sqrtf(32.0f) + 1e-6f);

#pragma unroll 2
    for (int mi = 0; mi < 512; ++mi) {
        const float* kp = kbase + mi * DD;
        const float* vp = vbase + mi * DD;

        float4 kf[8];
#pragma unroll
        for (int p = 0; p < 8; ++p) kf[p] = *(const float4*)(kp + p * 4);

        float re[4] = {0.f, 0.f, 0.f, 0.f};
        float im[4] = {0.f, 0.f, 0.f, 0.f};
#pragma unroll
        for (int p = 0; p < 8; ++p) {
            const float4 kk = kf[p];
            const float4 qq = qv[p];
            const int s = p & 3;
            re[s] += qq.x * kk.x + qq.y * kk.y + qq.z * kk.z + qq.w * kk.w;
            im[s] += qq.y * kk.x - qq.x * kk.y + qq.w * kk.z - qq.z * kk.w;
        }
        const float reT = (re[0] + re[1]) + (re[2] + re[3]);
        const float imT = (im[0] + im[1]) + (im[2] + im[3]);
        const float r2  = reT * reT + imT * imT + 1e-37f;
        const float w   = 0.5f + 0.5f * reT * rsqrtf(r2);
        const float e   = __expf(w * inv_s);
        denom += e;
#pragma unroll
        for (int p = 0; p < 8; ++p) {
            const float4 vv = *(const float4*)(vp + p * 4);
            av[p].x += e * vv.x;
            av[p].y += e * vv.y;
            av[p].z += e * vv.z;
            av[p].w += e * vv.w;
        }
    }

    __shared__ float red[4][64][34];
#pragma unroll
    for (int p = 0; p < 8; ++p) {
        red[wave][lane][p * 4 + 0] = av[p].x;
        red[wave][lane][p * 4 + 1] = av[p].y;
        red[wave][lane][p * 4 + 2] = av[p].z;
        red[wave][lane][p * 4 + 3] = av[p].w;
    }
    red[wave][lane][32] = denom;
    __syncthreads();

    const int row = tid >> 2;   // 0..63
    const int jg  = tid & 3;
    const float den = red[0][row][32] + red[1][row][32] + red[2][row][32] + red[3][row][32];
    const float rden = 1.0f / den;
    const int nrow = ntile * 64 + row;
    float* op = outp + (size_t)(b * NN + nrow) * DD + h * 32;
#pragma unroll
    for (int jj = 0; jj < 8; ++jj) {
        int j = jg * 8 + jj;
        float s = red[0][row][j] + red[1][row][j] + red[2][row][j] + red[3][row][j];
        op[j] = s * rden;
    }
}

// ---------------------------------------------------------------------------
// K3: gate MLP + in-place scale.  One wave per (b,n) row; lane j <-> hidden j.
// ---------------------------------------------------------------------------
__global__ __launch_bounds__(256) void gate_kernel(
    float* __restrict__ out,
    const float* __restrict__ Wg1, const float* __restrict__ Bg1,
    const float* __restrict__ Wg2, const float* __restrict__ Bg2)
{
    const int tid  = threadIdx.x;
    const int wave = tid >> 6;
    const int lane = tid & 63;
    const int row  = blockIdx.x * 4 + wave;   // 0..4095
    float* orow = out + (size_t)row * DD;

    const float* w1 = Wg1 + (size_t)lane * DD;
    float s0 = 0.f, s1 = 0.f, s2 = 0.f, s3 = 0.f;
#pragma unroll 8
    for (int q = 0; q < 64; ++q) {
        float4 o = *(const float4*)(orow + q * 4);
        float4 w = *(const float4*)(w1 + q * 4);
        s0 += o.x * w.x;
        s1 += o.y * w.y;
        s2 += o.z * w.z;
        s3 += o.w * w.w;
    }
    float s = (s0 + s1) + (s2 + s3) + Bg1[lane];
    float hh = s / (1.0f + __expf(-s));        // SiLU
    float t = hh * Wg2[lane];
#pragma unroll
    for (int off = 32; off >= 1; off >>= 1) t += __shfl_xor(t, off, 64);
    const float g = 1.0f / (1.0f + __expf(-(t + Bg2[0])));   // sigmoid

    float4 o = *(const float4*)(orow + lane * 4);
    o.x *= g; o.y *= g; o.z *= g; o.w *= g;
    *(float4*)(orow + lane * 4) = o;
}

// ---------------------------------------------------------------------------
extern "C" void kernel_launch(void* const* d_in, const int* in_sizes, int n_in,
                              void* d_out, int out_size, void* d_ws, size_t ws_size,
                              hipStream_t stream) {
    (void)in_sizes; (void)n_in; (void)out_size; (void)ws_size;
    const float* x   = (const float*)d_in[0];
    const float* wq  = (const float*)d_in[1];
    const float* bq  = (const float*)d_in[2];
    const float* wk  = (const float*)d_in[3];
    const float* bk  = (const float*)d_in[4];
    const float* wv  = (const float*)d_in[5];
    const float* bv  = (const float*)d_in[6];
    const float* wg1 = (const float*)d_in[7];
    const float* bg1 = (const float*)d_in[8];
    const float* wg2 = (const float*)d_in[9];
    const float* bg2 = (const float*)d_in[10];
    float* out = (float*)d_out;

    float* Q = (float*)d_ws;
    float* K = Q + (size_t)BB * NN * DD;
    float* V = K + (size_t)BB * NN * DD;

    qkv_gemm<<<dim3(64, 4, 3), 256, 0, stream>>>(x, wq, wk, wv, bq, bk, bv, Q, K, V);
    attn_kernel<<<dim3(512), 256, 0, stream>>>(Q, K, V, out);
    gate_kernel<<<dim3(1024), 256, 0, stream>>>(out, wg1, bg1, wg2, bg2);
}

// Round 2
// 122.506 us; speedup vs baseline: 4.5970x; 4.5970x over previous
//
#include <hip/hip_runtime.h>
#include <hip/hip_bf16.h>
#include <math.h>

#define BB 2
#define NN 2048
#define DD 256
#define HH 8

typedef __attribute__((ext_vector_type(8))) short bfrag8;
typedef __attribute__((ext_vector_type(4))) short bfrag4;
typedef __attribute__((ext_vector_type(4))) float f32x4;
typedef __attribute__((ext_vector_type(4))) unsigned short us4;

__device__ __forceinline__ unsigned short bf16rn(float f) {
    union { float f; unsigned u; } un; un.f = f;
    unsigned r = un.u + 0x7FFFu + ((un.u >> 16) & 1u);
    return (unsigned short)(r >> 16);
}

__device__ __forceinline__ f32x4 mfma16(bfrag4 a, bfrag4 b, f32x4 c) {
#if __has_builtin(__builtin_amdgcn_mfma_f32_16x16x16_bf16)
    return __builtin_amdgcn_mfma_f32_16x16x16_bf16(a, b, c, 0, 0, 0);
#else
    return __builtin_amdgcn_mfma_f32_16x16x16bf16_1k(a, b, c, 0, 0, 0);
#endif
}

// ---------------------------------------------------------------------------
// K1: fused QKV projection, f32 accumulate, bf16 outputs in MFMA-friendly
// layouts.  z=0 -> Qb + Qpb (pair-swizzled: Q'[2p]=Q[2p+1], Q'[2p+1]=-Q[2p]);
// z=1 -> Kb (row-major bf16); z=2 -> Vb pre-tiled for 16x16x16 B-fragments:
//   Vb[(b*8+h)*65536 + ((t*2+dt)*64 + 16*g + c)*4 + j] = V[m][h*32+16*dt+c],
//   with m = 16*t + 4*g + j.
// ---------------------------------------------------------------------------
__global__ __launch_bounds__(256) void qkv_gemm(
    const float* __restrict__ X,
    const float* __restrict__ Wq, const float* __restrict__ Wk, const float* __restrict__ Wv,
    const float* __restrict__ bq, const float* __restrict__ bk, const float* __restrict__ bv,
    unsigned short* __restrict__ Qb, unsigned short* __restrict__ Qpb,
    unsigned short* __restrict__ Kb, unsigned short* __restrict__ Vb)
{
    const int tid = threadIdx.x;
    const int z = blockIdx.z;
    const float* Wm = (z == 0) ? Wq : (z == 1) ? Wk : Wv;
    const float* bm = (z == 0) ? bq : (z == 1) ? bk : bv;

    const int n0 = blockIdx.x * 64;
    const int c0 = blockIdx.y * 64;

    __shared__ float As[32][68];
    __shared__ float Bs[32][68];

    const int ty = tid >> 4;
    const int tx = tid & 15;

    float acc[4][4];
#pragma unroll
    for (int i = 0; i < 4; ++i)
#pragma unroll
        for (int j = 0; j < 4; ++j) acc[i][j] = 0.f;

    for (int k0 = 0; k0 < DD; k0 += 32) {
        __syncthreads();
#pragma unroll
        for (int u = 0; u < 2; ++u) {
            int i   = tid * 2 + u;
            int row = i >> 3;
            int cc  = (i & 7) << 2;
            float4 xv = *(const float4*)(X  + (size_t)(n0 + row) * DD + k0 + cc);
            As[cc + 0][row] = xv.x;
            As[cc + 1][row] = xv.y;
            As[cc + 2][row] = xv.z;
            As[cc + 3][row] = xv.w;
            float4 wv = *(const float4*)(Wm + (size_t)(c0 + row) * DD + k0 + cc);
            Bs[cc + 0][row] = wv.x;
            Bs[cc + 1][row] = wv.y;
            Bs[cc + 2][row] = wv.z;
            Bs[cc + 3][row] = wv.w;
        }
        __syncthreads();
#pragma unroll
        for (int kk = 0; kk < 32; ++kk) {
            float4 a = *(const float4*)&As[kk][ty * 4];
            float4 b = *(const float4*)&Bs[kk][tx * 4];
            const float av[4] = {a.x, a.y, a.z, a.w};
            const float bw[4] = {b.x, b.y, b.z, b.w};
#pragma unroll
            for (int i = 0; i < 4; ++i)
#pragma unroll
                for (int j = 0; j < 4; ++j)
                    acc[i][j] += av[i] * bw[j];
        }
    }

    float bias[4];
#pragma unroll
    for (int j = 0; j < 4; ++j) bias[j] = bm[c0 + tx * 4 + j];
    const int col0 = c0 + tx * 4;

    if (z == 2) {
#pragma unroll
        for (int i = 0; i < 4; ++i) {
            const int mrow = n0 + ty * 4 + i;
            const int b = mrow >> 11;
            const int m = mrow & (NN - 1);
            const int t = m >> 4, g = (m >> 2) & 3, j = m & 3;
#pragma unroll
            for (int jj = 0; jj < 4; ++jj) {
                const int dcol = col0 + jj;
                const int h = dcol >> 5, dd = dcol & 31;
                const int dt = dd >> 4, cc = dd & 15;
                const size_t idx = (size_t)(b * 8 + h) * 65536
                                 + (size_t)(((t * 2 + dt) * 64) + 16 * g + cc) * 4 + j;
                Vb[idx] = bf16rn(acc[i][jj] + bias[jj]);
            }
        }
    } else {
        unsigned short* Ob = (z == 0) ? Qb : Kb;
#pragma unroll
        for (int i = 0; i < 4; ++i) {
            const float q0 = acc[i][0] + bias[0];
            const float q1 = acc[i][1] + bias[1];
            const float q2 = acc[i][2] + bias[2];
            const float q3 = acc[i][3] + bias[3];
            const size_t base = (size_t)(n0 + ty * 4 + i) * DD + col0;
            us4 pk = { bf16rn(q0), bf16rn(q1), bf16rn(q2), bf16rn(q3) };
            *(us4*)(Ob + base) = pk;
            if (z == 0) {
                us4 pk2 = { bf16rn(q1), bf16rn(-q0), bf16rn(q3), bf16rn(-q2) };
                *(us4*)(Qpb + base) = pk2;
            }
        }
    }
}

// ---------------------------------------------------------------------------
// K2: MFMA phase attention.  Block = 4 waves = one (b,h) x 16 query rows.
// Wave `wave` handles keys [wave*512, wave*512+512).  Per 16-key tile:
//   S^T(re) = mfma_16x16x32(Kfrag, Qfrag),  S^T(im) = mfma(Kfrag, Q'frag)
//   w = 0.5*(1+re/|z|);  e = exp(w/(sqrt(32)+1e-6))   (no max-sub: arg<=0.177)
//   P (= S^T acc layout) is directly the A-fragment of mfma_16x16x16_bf16:
//   out_acc[dt] += P x Vfrag[dt].   LDS combine of 4 waves at the end.
// ---------------------------------------------------------------------------
__global__ __launch_bounds__(256) void attn_mfma(
    const unsigned short* __restrict__ Qb, const unsigned short* __restrict__ Qpb,
    const unsigned short* __restrict__ Kb, const unsigned short* __restrict__ Vb,
    float* __restrict__ outp)
{
    const int tid  = threadIdx.x;
    const int wave = tid >> 6, lane = tid & 63;
    const int g = lane >> 4, c = lane & 15;
    const int bid = blockIdx.x;
    const int bh = bid >> 7, qt = bid & 127;
    const int b = bh >> 3, h = bh & 7;

    const size_t qoff = (size_t)(b * NN + qt * 16 + c) * DD + h * 32 + 8 * g;
    const bfrag8 qf  = *(const bfrag8*)(Qb  + qoff);
    const bfrag8 qpf = *(const bfrag8*)(Qpb + qoff);

    const unsigned short* kptr = Kb + (size_t)(b * NN + wave * 512 + c) * DD + h * 32 + 8 * g;
    const unsigned short* vptr = Vb + (size_t)(b * 8 + h) * 65536 + (size_t)wave * 16384 + lane * 4;

    f32x4 o0 = {0.f, 0.f, 0.f, 0.f};
    f32x4 o1 = {0.f, 0.f, 0.f, 0.f};
    const f32x4 zero = {0.f, 0.f, 0.f, 0.f};
    float denom = 0.f;
    const float SC = 0.5f / (sqrtf(32.0f) + 1e-6f);   // exp arg = SC*(1 + re/|z|)

#pragma unroll 2
    for (int tt = 0; tt < 32; ++tt) {
        const bfrag8 kf  = *(const bfrag8*)kptr;
        kptr += 16 * DD;
        const bfrag4 vf0 = *(const bfrag4*)vptr;
        const bfrag4 vf1 = *(const bfrag4*)(vptr + 256);
        vptr += 512;

        f32x4 re = __builtin_amdgcn_mfma_f32_16x16x32_bf16(kf, qf,  zero, 0, 0, 0);
        f32x4 im = __builtin_amdgcn_mfma_f32_16x16x32_bf16(kf, qpf, zero, 0, 0, 0);

        float e[4];
#pragma unroll
        for (int r = 0; r < 4; ++r) {
            const float rr = re[r], ii = im[r];
            const float r2 = fmaf(rr, rr, fmaf(ii, ii, 1e-30f));
            const float tq = rr * __builtin_amdgcn_rsqf(r2);
            const float ex = __expf(fmaf(SC, tq, SC));
            denom += ex;
            e[r] = ex;
        }
        bfrag4 pf;
        pf[0] = (short)bf16rn(e[0]);
        pf[1] = (short)bf16rn(e[1]);
        pf[2] = (short)bf16rn(e[2]);
        pf[3] = (short)bf16rn(e[3]);

        o0 = mfma16(pf, vf0, o0);
        o1 = mfma16(pf, vf1, o1);
    }

    // denom currently per-lane for q=c over this wave's keys & this g-group's m's
    denom += __shfl_xor(denom, 16, 64);
    denom += __shfl_xor(denom, 32, 64);

    __shared__ float cO[4][16][33];
    __shared__ float cD[4][16];
#pragma unroll
    for (int r = 0; r < 4; ++r) {
        cO[wave][4 * g + r][c]      = o0[r];
        cO[wave][4 * g + r][16 + c] = o1[r];
    }
    if (g == 0) cD[wave][c] = denom;
    __syncthreads();

    const int q  = tid >> 4;   // 0..15
    const int dp = tid & 15;   // 0..15 -> d = 2dp, 2dp+1
    const float den = cD[0][q] + cD[1][q] + cD[2][q] + cD[3][q];
    const float rden = 1.0f / den;
    const float s0 = cO[0][q][2 * dp]     + cO[1][q][2 * dp]
                   + cO[2][q][2 * dp]     + cO[3][q][2 * dp];
    const float s1 = cO[0][q][2 * dp + 1] + cO[1][q][2 * dp + 1]
                   + cO[2][q][2 * dp + 1] + cO[3][q][2 * dp + 1];
    float2 ov = make_float2(s0 * rden, s1 * rden);
    *(float2*)(outp + (size_t)(b * NN + qt * 16 + q) * DD + h * 32 + 2 * dp) = ov;
}

// ---------------------------------------------------------------------------
// K3: gate MLP + in-place scale (unchanged).
// ---------------------------------------------------------------------------
__global__ __launch_bounds__(256) void gate_kernel(
    float* __restrict__ out,
    const float* __restrict__ Wg1, const float* __restrict__ Bg1,
    const float* __restrict__ Wg2, const float* __restrict__ Bg2)
{
    const int tid  = threadIdx.x;
    const int wave = tid >> 6;
    const int lane = tid & 63;
    const int row  = blockIdx.x * 4 + wave;
    float* orow = out + (size_t)row * DD;

    const float* w1 = Wg1 + (size_t)lane * DD;
    float s0 = 0.f, s1 = 0.f, s2 = 0.f, s3 = 0.f;
#pragma unroll 8
    for (int q = 0; q < 64; ++q) {
        float4 o = *(const float4*)(orow + q * 4);
        float4 w = *(const float4*)(w1 + q * 4);
        s0 += o.x * w.x;
        s1 += o.y * w.y;
        s2 += o.z * w.z;
        s3 += o.w * w.w;
    }
    float s = (s0 + s1) + (s2 + s3) + Bg1[lane];
    float hh = s / (1.0f + __expf(-s));
    float t = hh * Wg2[lane];
#pragma unroll
    for (int off = 32; off >= 1; off >>= 1) t += __shfl_xor(t, off, 64);
    const float gsc = 1.0f / (1.0f + __expf(-(t + Bg2[0])));

    float4 o = *(const float4*)(orow + lane * 4);
    o.x *= gsc; o.y *= gsc; o.z *= gsc; o.w *= gsc;
    *(float4*)(orow + lane * 4) = o;
}

// ---------------------------------------------------------------------------
extern "C" void kernel_launch(void* const* d_in, const int* in_sizes, int n_in,
                              void* d_out, int out_size, void* d_ws, size_t ws_size,
                              hipStream_t stream) {
    (void)in_sizes; (void)n_in; (void)out_size; (void)ws_size;
    const float* x   = (const float*)d_in[0];
    const float* wq  = (const float*)d_in[1];
    const float* bq  = (const float*)d_in[2];
    const float* wk  = (const float*)d_in[3];
    const float* bk  = (const float*)d_in[4];
    const float* wv  = (const float*)d_in[5];
    const float* bv  = (const float*)d_in[6];
    const float* wg1 = (const float*)d_in[7];
    const float* bg1 = (const float*)d_in[8];
    const float* wg2 = (const float*)d_in[9];
    const float* bg2 = (const float*)d_in[10];
    float* out = (float*)d_out;

    unsigned short* Qb  = (unsigned short*)d_ws;
    unsigned short* Qpb = Qb  + (size_t)BB * NN * DD;
    unsigned short* Kb  = Qpb + (size_t)BB * NN * DD;
    unsigned short* Vb  = Kb  + (size_t)BB * NN * DD;

    qkv_gemm<<<dim3(64, 4, 3), 256, 0, stream>>>(x, wq, wk, wv, bq, bk, bv, Qb, Qpb, Kb, Vb);
    attn_mfma<<<dim3(2048), 256, 0, stream>>>(Qb, Qpb, Kb, Vb, out);
    gate_kernel<<<dim3(1024), 256, 0, stream>>>(out, wg1, bg1, wg2, bg2);
}

// Round 3
// 113.007 us; speedup vs baseline: 4.9834x; 1.0841x over previous
//
#include <hip/hip_runtime.h>
#include <hip/hip_bf16.h>
#include <math.h>

#define BB 2
#define NN 2048
#define DD 256
#define HH 8

typedef __attribute__((ext_vector_type(8))) short bfrag8;
typedef __attribute__((ext_vector_type(4))) short bfrag4;
typedef __attribute__((ext_vector_type(4))) float f32x4;
typedef __attribute__((ext_vector_type(4))) unsigned short us4;
typedef __attribute__((ext_vector_type(8))) short s8v;

__device__ __forceinline__ unsigned short bf16rn(float f) {
    union { float f; unsigned u; } un; un.f = f;
    unsigned r = un.u + 0x7FFFu + ((un.u >> 16) & 1u);
    return (unsigned short)(r >> 16);
}

__device__ __forceinline__ float fexp2(float x) {
#if __has_builtin(__builtin_amdgcn_exp2f)
    return __builtin_amdgcn_exp2f(x);
#else
    return __expf(x * 0.69314718056f);
#endif
}

__device__ __forceinline__ f32x4 mfma16(bfrag4 a, bfrag4 b, f32x4 c) {
#if __has_builtin(__builtin_amdgcn_mfma_f32_16x16x16_bf16)
    return __builtin_amdgcn_mfma_f32_16x16x16_bf16(a, b, c, 0, 0, 0);
#else
    return __builtin_amdgcn_mfma_f32_16x16x16bf16_1k(a, b, c, 0, 0, 0);
#endif
}

// ---------------------------------------------------------------------------
// K0: convert X (4096x256) and Wq/Wk/Wv (256x256 each) f32 -> bf16.
// 8 elements per thread; 155648 threads = 608 blocks.
// ---------------------------------------------------------------------------
__global__ __launch_bounds__(256) void cvt_inputs(
    const float* __restrict__ X,
    const float* __restrict__ Wq, const float* __restrict__ Wk, const float* __restrict__ Wv,
    unsigned short* __restrict__ Xb,
    unsigned short* __restrict__ Wqb, unsigned short* __restrict__ Wkb, unsigned short* __restrict__ Wvb)
{
    const int i = blockIdx.x * 256 + threadIdx.x;
    const float* src; unsigned short* dst; size_t off;
    if (i < 131072)      { src = X;  dst = Xb;  off = (size_t)i * 8; }
    else if (i < 139264) { src = Wq; dst = Wqb; off = (size_t)(i - 131072) * 8; }
    else if (i < 147456) { src = Wk; dst = Wkb; off = (size_t)(i - 139264) * 8; }
    else                 { src = Wv; dst = Wvb; off = (size_t)(i - 147456) * 8; }
    float4 a = *(const float4*)(src + off);
    float4 b = *(const float4*)(src + off + 4);
    us4 lo = { bf16rn(a.x), bf16rn(a.y), bf16rn(a.z), bf16rn(a.w) };
    us4 hi = { bf16rn(b.x), bf16rn(b.y), bf16rn(b.z), bf16rn(b.w) };
    *(us4*)(dst + off)     = lo;
    *(us4*)(dst + off + 4) = hi;
}

// ---------------------------------------------------------------------------
// K1: MFMA QKV GEMM.  Block tile 64 rows x 64 cols, 4 waves (16 rows each).
// D = mfma(A=Wfrag, B=Xfrag): lane holds 4 consecutive output cols of one row
//   (n = base + (lane&15), cols = 16j + 4*(lane>>4) + r)  -> us4 stores and
// lane-local Qp pair swizzle.  LDS: [64 rows][64 bf16] (128B stride), XOR
// swizzle byte ^= (row&7)<<4 -> conflict-free ds_read_b128 fragments.
// z = 0:Q (writes Qb+Qpb), 1:K, 2:V (writes tiled Vb).
// ---------------------------------------------------------------------------
__global__ __launch_bounds__(256) void qkv_mfma(
    const unsigned short* __restrict__ Xb,
    const unsigned short* __restrict__ Wqb, const unsigned short* __restrict__ Wkb,
    const unsigned short* __restrict__ Wvb,
    const float* __restrict__ bq, const float* __restrict__ bk, const float* __restrict__ bv,
    unsigned short* __restrict__ Qb, unsigned short* __restrict__ Qpb,
    unsigned short* __restrict__ Kb, unsigned short* __restrict__ Vb)
{
    const int tid  = threadIdx.x;
    const int z    = blockIdx.z;
    const unsigned short* Wm = (z == 0) ? Wqb : (z == 1) ? Wkb : Wvb;
    const float*          bm = (z == 0) ? bq  : (z == 1) ? bk  : bv;

    const int Mbase = blockIdx.x * 64;
    const int Nbase = blockIdx.y * 64;

    __shared__ unsigned short Xs[64 * 64];   // row stride 64 shorts = 128B
    __shared__ unsigned short Ws[64 * 64];

    const int wave = tid >> 6, lane = tid & 63;
    const int c = lane & 15, g = lane >> 4;

    // staging addresses (constant per thread; k advances by 32 each step)
    const int srow = tid >> 2;          // 0..63
    const int sq   = tid & 3;           // 16B chunk
    const int soff = ((srow * 128 + sq * 16) ^ ((srow & 7) << 4));
    const unsigned short* gx = Xb + (size_t)(Mbase + srow) * DD + sq * 8;
    const unsigned short* gw = Wm + (size_t)(Nbase + srow) * DD + sq * 8;

    // fragment read offsets (constant)
    const int xrow = 16 * wave + c;
    const int xoff = ((xrow * 128 + g * 16) ^ ((xrow & 7) << 4));
    int woff[4];
#pragma unroll
    for (int j = 0; j < 4; ++j) {
        const int wrow = 16 * j + c;
        woff[j] = ((wrow * 128 + g * 16) ^ ((wrow & 7) << 4));
    }

    f32x4 acc[4];
#pragma unroll
    for (int j = 0; j < 4; ++j) acc[j] = (f32x4){0.f, 0.f, 0.f, 0.f};

    for (int k0 = 0; k0 < DD; k0 += 32) {
        *(s8v*)((char*)Xs + soff) = *(const s8v*)(gx + k0);
        *(s8v*)((char*)Ws + soff) = *(const s8v*)(gw + k0);
        __syncthreads();
        const bfrag8 xf = *(const bfrag8*)((const char*)Xs + xoff);
#pragma unroll
        for (int j = 0; j < 4; ++j) {
            const bfrag8 wf = *(const bfrag8*)((const char*)Ws + woff[j]);
            acc[j] = __builtin_amdgcn_mfma_f32_16x16x32_bf16(wf, xf, acc[j], 0, 0, 0);
        }
        __syncthreads();
    }

    // epilogue
    const int n = Mbase + xrow;               // global row (b*N + m)
    const int bb = n >> 11, m = n & (NN - 1);
#pragma unroll
    for (int j = 0; j < 4; ++j) {
        const int col0 = Nbase + 16 * j + 4 * g;
        float4 bias = *(const float4*)(bm + col0);
        float v0 = acc[j][0] + bias.x;
        float v1 = acc[j][1] + bias.y;
        float v2 = acc[j][2] + bias.z;
        float v3 = acc[j][3] + bias.w;
        if (z == 2) {
            const int t = m >> 4, gg = (m >> 2) & 3, jj = m & 3;
            const int h = col0 >> 5, dt = (col0 >> 4) & 1, cc0 = col0 & 15;
            const size_t base = (size_t)(bb * 8 + h) * 65536
                              + (size_t)(((t * 2 + dt) * 64) + 16 * gg) * 4 + jj;
            Vb[base + (size_t)(cc0 + 0) * 4] = bf16rn(v0);
            Vb[base + (size_t)(cc0 + 1) * 4] = bf16rn(v1);
            Vb[base + (size_t)(cc0 + 2) * 4] = bf16rn(v2);
            Vb[base + (size_t)(cc0 + 3) * 4] = bf16rn(v3);
        } else {
            us4 pk = { bf16rn(v0), bf16rn(v1), bf16rn(v2), bf16rn(v3) };
            unsigned short* Ob = (z == 0) ? Qb : Kb;
            *(us4*)(Ob + (size_t)n * DD + col0) = pk;
            if (z == 0) {
                us4 pk2 = { bf16rn(v1), bf16rn(-v0), bf16rn(v3), bf16rn(-v2) };
                *(us4*)(Qpb + (size_t)n * DD + col0) = pk2;
            }
        }
    }
}

// ---------------------------------------------------------------------------
// K2: MFMA phase attention (e-chain slimmed: softmax scale-invariance drops
// the constant exp term; exp2 direct).
// ---------------------------------------------------------------------------
__global__ __launch_bounds__(256) void attn_mfma(
    const unsigned short* __restrict__ Qb, const unsigned short* __restrict__ Qpb,
    const unsigned short* __restrict__ Kb, const unsigned short* __restrict__ Vb,
    float* __restrict__ outp)
{
    const int tid  = threadIdx.x;
    const int wave = tid >> 6, lane = tid & 63;
    const int g = lane >> 4, c = lane & 15;
    const int bid = blockIdx.x;
    const int bh = bid >> 7, qt = bid & 127;
    const int b = bh >> 3, h = bh & 7;

    const size_t qoff = (size_t)(b * NN + qt * 16 + c) * DD + h * 32 + 8 * g;
    const bfrag8 qf  = *(const bfrag8*)(Qb  + qoff);
    const bfrag8 qpf = *(const bfrag8*)(Qpb + qoff);

    const unsigned short* kptr = Kb + (size_t)(b * NN + wave * 512 + c) * DD + h * 32 + 8 * g;
    const unsigned short* vptr = Vb + (size_t)(b * 8 + h) * 65536 + (size_t)wave * 16384 + lane * 4;

    f32x4 o0 = {0.f, 0.f, 0.f, 0.f};
    f32x4 o1 = {0.f, 0.f, 0.f, 0.f};
    const f32x4 zero = {0.f, 0.f, 0.f, 0.f};
    float denom = 0.f;
    const float C2 = 0.72134752044448f / (sqrtf(32.0f) + 1e-6f);  // 0.5*log2e/s

#pragma unroll 2
    for (int tt = 0; tt < 32; ++tt) {
        const bfrag8 kf  = *(const bfrag8*)kptr;
        kptr += 16 * DD;
        const bfrag4 vf0 = *(const bfrag4*)vptr;
        const bfrag4 vf1 = *(const bfrag4*)(vptr + 256);
        vptr += 512;

        f32x4 re = __builtin_amdgcn_mfma_f32_16x16x32_bf16(kf, qf,  zero, 0, 0, 0);
        f32x4 im = __builtin_amdgcn_mfma_f32_16x16x32_bf16(kf, qpf, zero, 0, 0, 0);

        float ex[4];
#pragma unroll
        for (int r = 0; r < 4; ++r) {
            const float rr = re[r], ii = im[r];
            const float r2 = fmaf(rr, rr, fmaf(ii, ii, 1e-30f));
            const float tq = rr * __builtin_amdgcn_rsqf(r2);
            ex[r] = fexp2(tq * C2);
        }
        denom += (ex[0] + ex[1]) + (ex[2] + ex[3]);
        bfrag4 pf;
        pf[0] = (short)bf16rn(ex[0]);
        pf[1] = (short)bf16rn(ex[1]);
        pf[2] = (short)bf16rn(ex[2]);
        pf[3] = (short)bf16rn(ex[3]);

        o0 = mfma16(pf, vf0, o0);
        o1 = mfma16(pf, vf1, o1);
    }

    denom += __shfl_xor(denom, 16, 64);
    denom += __shfl_xor(denom, 32, 64);

    __shared__ float cO[4][16][33];
    __shared__ float cD[4][16];
#pragma unroll
    for (int r = 0; r < 4; ++r) {
        cO[wave][4 * g + r][c]      = o0[r];
        cO[wave][4 * g + r][16 + c] = o1[r];
    }
    if (g == 0) cD[wave][c] = denom;
    __syncthreads();

    const int q  = tid >> 4;
    const int dp = tid & 15;
    const float den = cD[0][q] + cD[1][q] + cD[2][q] + cD[3][q];
    const float rden = 1.0f / den;
    const float s0 = cO[0][q][2 * dp]     + cO[1][q][2 * dp]
                   + cO[2][q][2 * dp]     + cO[3][q][2 * dp];
    const float s1 = cO[0][q][2 * dp + 1] + cO[1][q][2 * dp + 1]
                   + cO[2][q][2 * dp + 1] + cO[3][q][2 * dp + 1];
    float2 ov = make_float2(s0 * rden, s1 * rden);
    *(float2*)(outp + (size_t)(b * NN + qt * 16 + q) * DD + h * 32 + 2 * dp) = ov;
}

// ---------------------------------------------------------------------------
// K3: gate MLP + in-place scale (unchanged).
// ---------------------------------------------------------------------------
__global__ __launch_bounds__(256) void gate_kernel(
    float* __restrict__ out,
    const float* __restrict__ Wg1, const float* __restrict__ Bg1,
    const float* __restrict__ Wg2, const float* __restrict__ Bg2)
{
    const int tid  = threadIdx.x;
    const int wave = tid >> 6;
    const int lane = tid & 63;
    const int row  = blockIdx.x * 4 + wave;
    float* orow = out + (size_t)row * DD;

    const float* w1 = Wg1 + (size_t)lane * DD;
    float s0 = 0.f, s1 = 0.f, s2 = 0.f, s3 = 0.f;
#pragma unroll 8
    for (int q = 0; q < 64; ++q) {
        float4 o = *(const float4*)(orow + q * 4);
        float4 w = *(const float4*)(w1 + q * 4);
        s0 += o.x * w.x;
        s1 += o.y * w.y;
        s2 += o.z * w.z;
        s3 += o.w * w.w;
    }
    float s = (s0 + s1) + (s2 + s3) + Bg1[lane];
    float hh = s / (1.0f + __expf(-s));
    float t = hh * Wg2[lane];
#pragma unroll
    for (int off = 32; off >= 1; off >>= 1) t += __shfl_xor(t, off, 64);
    const float gsc = 1.0f / (1.0f + __expf(-(t + Bg2[0])));

    float4 o = *(const float4*)(orow + lane * 4);
    o.x *= gsc; o.y *= gsc; o.z *= gsc; o.w *= gsc;
    *(float4*)(orow + lane * 4) = o;
}

// ---------------------------------------------------------------------------
extern "C" void kernel_launch(void* const* d_in, const int* in_sizes, int n_in,
                              void* d_out, int out_size, void* d_ws, size_t ws_size,
                              hipStream_t stream) {
    (void)in_sizes; (void)n_in; (void)out_size; (void)ws_size;
    const float* x   = (const float*)d_in[0];
    const float* wq  = (const float*)d_in[1];
    const float* bq  = (const float*)d_in[2];
    const float* wk  = (const float*)d_in[3];
    const float* bk  = (const float*)d_in[4];
    const float* wv  = (const float*)d_in[5];
    const float* bv  = (const float*)d_in[6];
    const float* wg1 = (const float*)d_in[7];
    const float* bg1 = (const float*)d_in[8];
    const float* wg2 = (const float*)d_in[9];
    const float* bg2 = (const float*)d_in[10];
    float* out = (float*)d_out;

    const size_t NE = (size_t)BB * NN * DD;   // 1048576
    unsigned short* Qb  = (unsigned short*)d_ws;
    unsigned short* Qpb = Qb  + NE;
    unsigned short* Kb  = Qpb + NE;
    unsigned short* Vb  = Kb  + NE;
    unsigned short* Xb  = Vb  + NE;
    unsigned short* Wqb = Xb  + NE;
    unsigned short* Wkb = Wqb + 65536;
    unsigned short* Wvb = Wkb + 65536;

    cvt_inputs<<<608, 256, 0, stream>>>(x, wq, wk, wv, Xb, Wqb, Wkb, Wvb);
    qkv_mfma<<<dim3(64, 4, 3), 256, 0, stream>>>(Xb, Wqb, Wkb, Wvb, bq, bk, bv,
                                                 Qb, Qpb, Kb, Vb);
    attn_mfma<<<dim3(2048), 256, 0, stream>>>(Qb, Qpb, Kb, Vb, out);
    gate_kernel<<<dim3(1024), 256, 0, stream>>>(out, wg1, bg1, wg2, bg2);
}

// Round 4
// 65.022 us; speedup vs baseline: 8.6611x; 1.7380x over previous
//
#include <hip/hip_runtime.h>
#include <hip/hip_bf16.h>
#include <math.h>

#define BB 2
#define NN 2048
#define DD 256
#define HH 8

typedef __attribute__((ext_vector_type(8))) short bfrag8;
typedef __attribute__((ext_vector_type(4))) short bfrag4;
typedef __attribute__((ext_vector_type(4))) float f32x4;
typedef __attribute__((ext_vector_type(4))) unsigned short us4;
typedef __attribute__((ext_vector_type(8))) short s8v;

__device__ __forceinline__ unsigned short bf16rn(float f) {
    union { float f; unsigned u; } un; un.f = f;
    unsigned r = un.u + 0x7FFFu + ((un.u >> 16) & 1u);
    return (unsigned short)(r >> 16);
}

__device__ __forceinline__ f32x4 mfma16(bfrag4 a, bfrag4 b, f32x4 c) {
#if __has_builtin(__builtin_amdgcn_mfma_f32_16x16x16_bf16)
    return __builtin_amdgcn_mfma_f32_16x16x16_bf16(a, b, c, 0, 0, 0);
#else
    return __builtin_amdgcn_mfma_f32_16x16x16bf16_1k(a, b, c, 0, 0, 0);
#endif
}

// pair swizzle for the imag dot: {q0,q1,...} -> {q1,-q0,q3,-q2,...} (bf16 neg = sign XOR)
__device__ __forceinline__ bfrag8 pairswz(bfrag8 q) {
    union { bfrag8 f; unsigned u[4]; } a, r;
    a.f = q;
#pragma unroll
    for (int i = 0; i < 4; ++i) {
        unsigned d = a.u[i];
        r.u[i] = ((d >> 16) | (d << 16)) ^ 0x80000000u;
    }
    return r.f;
}

// w-chain: y = SC2 * re/|z|;  P = exp(y) via cubic Taylor (|y|<=0.0884);
// pack 4 probs to bf16 pairs with v_cvt_pk_bf16_f32.
__device__ __forceinline__ bfrag4 expchain(f32x4 re, f32x4 im, float SC2) {
    float p[4];
#pragma unroll
    for (int r = 0; r < 4; ++r) {
        const float rr = re[r], ii = im[r];
        const float r2 = fmaf(rr, rr, fmaf(ii, ii, 1e-30f));
        const float y  = SC2 * rr * __builtin_amdgcn_rsqf(r2);
        const float a  = fmaf(y, 0.16666667f, 0.5f);
        const float bq = fmaf(y, a, 1.0f);
        p[r] = fmaf(y, bq, 1.0f);
    }
    unsigned lo, hi;
    asm("v_cvt_pk_bf16_f32 %0, %1, %2" : "=v"(lo) : "v"(p[0]), "v"(p[1]));
    asm("v_cvt_pk_bf16_f32 %0, %1, %2" : "=v"(hi) : "v"(p[2]), "v"(p[3]));
    union { unsigned u[2]; bfrag4 f; } pu;
    pu.u[0] = lo; pu.u[1] = hi;
    return pu.f;
}

// ---------------------------------------------------------------------------
// K0: convert X and Wq/Wk/Wv f32 -> bf16.
// ---------------------------------------------------------------------------
__global__ __launch_bounds__(256) void cvt_inputs(
    const float* __restrict__ X,
    const float* __restrict__ Wq, const float* __restrict__ Wk, const float* __restrict__ Wv,
    unsigned short* __restrict__ Xb,
    unsigned short* __restrict__ Wqb, unsigned short* __restrict__ Wkb, unsigned short* __restrict__ Wvb)
{
    const int i = blockIdx.x * 256 + threadIdx.x;
    const float* src; unsigned short* dst; size_t off;
    if (i < 131072)      { src = X;  dst = Xb;  off = (size_t)i * 8; }
    else if (i < 139264) { src = Wq; dst = Wqb; off = (size_t)(i - 131072) * 8; }
    else if (i < 147456) { src = Wk; dst = Wkb; off = (size_t)(i - 139264) * 8; }
    else                 { src = Wv; dst = Wvb; off = (size_t)(i - 147456) * 8; }
    float4 a = *(const float4*)(src + off);
    float4 b = *(const float4*)(src + off + 4);
    us4 lo = { bf16rn(a.x), bf16rn(a.y), bf16rn(a.z), bf16rn(a.w) };
    us4 hi = { bf16rn(b.x), bf16rn(b.y), bf16rn(b.z), bf16rn(b.w) };
    *(us4*)(dst + off)     = lo;
    *(us4*)(dst + off + 4) = hi;
}

// ---------------------------------------------------------------------------
// K1: MFMA QKV GEMM (64x64 tile, XOR-swizzled LDS).  z=0:Q, 1:K, 2:V(tiled).
// V tile layout: Vb[bh*65536 + T*512 + lane*8 + dt*4 + j] =
//   V[m=16T+4*(lane>>4)+j][h*32 + 16dt + (lane&15)]  -> one 16B load per tile.
// ---------------------------------------------------------------------------
__global__ __launch_bounds__(256) void qkv_mfma(
    const unsigned short* __restrict__ Xb,
    const unsigned short* __restrict__ Wqb, const unsigned short* __restrict__ Wkb,
    const unsigned short* __restrict__ Wvb,
    const float* __restrict__ bq, const float* __restrict__ bk, const float* __restrict__ bv,
    unsigned short* __restrict__ Qb, unsigned short* __restrict__ Kb, unsigned short* __restrict__ Vb)
{
    const int tid  = threadIdx.x;
    const int z    = blockIdx.z;
    const unsigned short* Wm = (z == 0) ? Wqb : (z == 1) ? Wkb : Wvb;
    const float*          bm = (z == 0) ? bq  : (z == 1) ? bk  : bv;

    const int Mbase = blockIdx.x * 64;
    const int Nbase = blockIdx.y * 64;

    __shared__ unsigned short Xs[64 * 64];
    __shared__ unsigned short Ws[64 * 64];

    const int wave = tid >> 6, lane = tid & 63;
    const int c = lane & 15, g = lane >> 4;

    const int srow = tid >> 2;
    const int sq   = tid & 3;
    const int soff = ((srow * 128 + sq * 16) ^ ((srow & 7) << 4));
    const unsigned short* gx = Xb + (size_t)(Mbase + srow) * DD + sq * 8;
    const unsigned short* gw = Wm + (size_t)(Nbase + srow) * DD + sq * 8;

    const int xrow = 16 * wave + c;
    const int xoff = ((xrow * 128 + g * 16) ^ ((xrow & 7) << 4));
    int woff[4];
#pragma unroll
    for (int j = 0; j < 4; ++j) {
        const int wrow = 16 * j + c;
        woff[j] = ((wrow * 128 + g * 16) ^ ((wrow & 7) << 4));
    }

    f32x4 acc[4];
#pragma unroll
    for (int j = 0; j < 4; ++j) acc[j] = (f32x4){0.f, 0.f, 0.f, 0.f};

    for (int k0 = 0; k0 < DD; k0 += 32) {
        *(s8v*)((char*)Xs + soff) = *(const s8v*)(gx + k0);
        *(s8v*)((char*)Ws + soff) = *(const s8v*)(gw + k0);
        __syncthreads();
        const bfrag8 xf = *(const bfrag8*)((const char*)Xs + xoff);
#pragma unroll
        for (int j = 0; j < 4; ++j) {
            const bfrag8 wf = *(const bfrag8*)((const char*)Ws + woff[j]);
            acc[j] = __builtin_amdgcn_mfma_f32_16x16x32_bf16(wf, xf, acc[j], 0, 0, 0);
        }
        __syncthreads();
    }

    const int n = Mbase + xrow;
    const int bb = n >> 11, m = n & (NN - 1);
#pragma unroll
    for (int j = 0; j < 4; ++j) {
        const int col0 = Nbase + 16 * j + 4 * g;
        float4 bias = *(const float4*)(bm + col0);
        float v0 = acc[j][0] + bias.x;
        float v1 = acc[j][1] + bias.y;
        float v2 = acc[j][2] + bias.z;
        float v3 = acc[j][3] + bias.w;
        if (z == 2) {
            const int t = m >> 4, gg = (m >> 2) & 3, jj = m & 3;
            const int h2 = col0 >> 5, dt = (col0 >> 4) & 1, cc0 = col0 & 15;
            const size_t base = (size_t)(bb * 8 + h2) * 65536
                              + (size_t)t * 512 + (size_t)(dt * 4 + jj);
            Vb[base + (size_t)(16 * gg + cc0 + 0) * 8] = bf16rn(v0);
            Vb[base + (size_t)(16 * gg + cc0 + 1) * 8] = bf16rn(v1);
            Vb[base + (size_t)(16 * gg + cc0 + 2) * 8] = bf16rn(v2);
            Vb[base + (size_t)(16 * gg + cc0 + 3) * 8] = bf16rn(v3);
        } else {
            us4 pk = { bf16rn(v0), bf16rn(v1), bf16rn(v2), bf16rn(v3) };
            unsigned short* Ob = (z == 0) ? Qb : Kb;
            *(us4*)(Ob + (size_t)n * DD + col0) = pk;
        }
    }
}

// ---------------------------------------------------------------------------
// K2: MFMA phase attention.  Block = 4 waves, 32 q-rows (2 q-tiles), each wave
// owns a 512-key chunk.  Per 16-key tile: 4x mfma32 (re/im x 2 q-tiles),
// Taylor-exp chain, cvt_pk pack, 3x mfma16 per q-tile (o_lo, o_hi, denom via
// ones-fragment).  Register prefetch of next K/V tile.  LDS combine of 4 waves.
// ---------------------------------------------------------------------------
__global__ __launch_bounds__(256, 4) void attn_mfma(
    const unsigned short* __restrict__ Qb, const unsigned short* __restrict__ Kb,
    const unsigned short* __restrict__ Vb, float* __restrict__ outp)
{
    const int tid  = threadIdx.x;
    const int wave = tid >> 6, lane = tid & 63;
    const int g = lane >> 4, c = lane & 15;
    const int bid = blockIdx.x;          // 1024
    const int bh = bid >> 6, qt = bid & 63;
    const int b = bh >> 3, h = bh & 7;

    const size_t qoff = (size_t)(b * NN + qt * 32 + c) * DD + h * 32 + 8 * g;
    const bfrag8 qf0  = *(const bfrag8*)(Qb + qoff);
    const bfrag8 qf1  = *(const bfrag8*)(Qb + qoff + 16 * DD);
    const bfrag8 qpf0 = pairswz(qf0);
    const bfrag8 qpf1 = pairswz(qf1);

    const unsigned short* kbase = Kb + (size_t)(b * NN + wave * 512 + c) * DD + h * 32 + 8 * g;
    const unsigned short* vbase = Vb + (size_t)bh * 65536 + (size_t)(wave * 32) * 512 + lane * 8;

    const f32x4 zero = {0.f, 0.f, 0.f, 0.f};
    f32x4 o00 = zero, o01 = zero, od0 = zero;
    f32x4 o10 = zero, o11 = zero, od1 = zero;
    const bfrag4 ones = { 0x3F80, 0x3F80, 0x3F80, 0x3F80 };
    const float SC2 = 0.5f / (sqrtf(32.0f) + 1e-6f);

    bfrag8 kf = *(const bfrag8*)kbase;
    bfrag8 vf = *(const bfrag8*)vbase;

    for (int tt = 0; tt < 32; ++tt) {
        const int nx = (tt + 1) & 31;
        const bfrag8 kf_n = *(const bfrag8*)(kbase + (size_t)nx * 16 * DD);
        const bfrag8 vf_n = *(const bfrag8*)(vbase + (size_t)nx * 512);

        f32x4 re0 = __builtin_amdgcn_mfma_f32_16x16x32_bf16(kf, qf0,  zero, 0, 0, 0);
        f32x4 im0 = __builtin_amdgcn_mfma_f32_16x16x32_bf16(kf, qpf0, zero, 0, 0, 0);
        f32x4 re1 = __builtin_amdgcn_mfma_f32_16x16x32_bf16(kf, qf1,  zero, 0, 0, 0);
        f32x4 im1 = __builtin_amdgcn_mfma_f32_16x16x32_bf16(kf, qpf1, zero, 0, 0, 0);

        const bfrag4 pf0 = expchain(re0, im0, SC2);
        const bfrag4 pf1 = expchain(re1, im1, SC2);

        union { bfrag8 v8; bfrag4 v4[2]; } vs; vs.v8 = vf;
        o00 = mfma16(pf0, vs.v4[0], o00);
        o01 = mfma16(pf0, vs.v4[1], o01);
        od0 = mfma16(pf0, ones,     od0);
        o10 = mfma16(pf1, vs.v4[0], o10);
        o11 = mfma16(pf1, vs.v4[1], o11);
        od1 = mfma16(pf1, ones,     od1);

        kf = kf_n; vf = vf_n;
    }

    __shared__ float cO[4][32][33];
    __shared__ float cD[4][32];
#pragma unroll
    for (int r = 0; r < 4; ++r) {
        cO[wave][4 * g + r][c]           = o00[r];
        cO[wave][4 * g + r][16 + c]      = o01[r];
        cO[wave][16 + 4 * g + r][c]      = o10[r];
        cO[wave][16 + 4 * g + r][16 + c] = o11[r];
    }
    if (c == 0) {
#pragma unroll
        for (int r = 0; r < 4; ++r) {
            cD[wave][4 * g + r]      = od0[r];
            cD[wave][16 + 4 * g + r] = od1[r];
        }
    }
    __syncthreads();

    const int q  = tid >> 3;   // 0..31
    const int dp = tid & 7;    // 0..7 -> d = 4dp..4dp+3
    const float den  = (cD[0][q] + cD[1][q]) + (cD[2][q] + cD[3][q]);
    const float rden = 1.0f / den;
    float4 s;
    s.x = ((cO[0][q][4 * dp + 0] + cO[1][q][4 * dp + 0]) + (cO[2][q][4 * dp + 0] + cO[3][q][4 * dp + 0])) * rden;
    s.y = ((cO[0][q][4 * dp + 1] + cO[1][q][4 * dp + 1]) + (cO[2][q][4 * dp + 1] + cO[3][q][4 * dp + 1])) * rden;
    s.z = ((cO[0][q][4 * dp + 2] + cO[1][q][4 * dp + 2]) + (cO[2][q][4 * dp + 2] + cO[3][q][4 * dp + 2])) * rden;
    s.w = ((cO[0][q][4 * dp + 3] + cO[1][q][4 * dp + 3]) + (cO[2][q][4 * dp + 3] + cO[3][q][4 * dp + 3])) * rden;
    *(float4*)(outp + (size_t)(b * NN + qt * 32 + q) * DD + h * 32 + 4 * dp) = s;
}

// ---------------------------------------------------------------------------
// K3: gate MLP + in-place scale.  Wg1 staged in LDS (pad 257 -> 2-way banks),
// 16 rows per block, wave-per-row-group, lane <-> hidden unit.
// ---------------------------------------------------------------------------
__global__ __launch_bounds__(256) void gate_kernel(
    float* __restrict__ out,
    const float* __restrict__ Wg1, const float* __restrict__ Bg1,
    const float* __restrict__ Wg2, const float* __restrict__ Bg2)
{
    __shared__ float Ws[64][257];
    const int tid = threadIdx.x;
#pragma unroll
    for (int pass = 0; pass < 16; ++pass) {
        const int i = pass * 256 + tid;          // float4 chunk id
        const int r = i >> 6, qd = i & 63;
        float4 w = *(const float4*)(Wg1 + r * DD + qd * 4);
        Ws[r][qd * 4 + 0] = w.x;
        Ws[r][qd * 4 + 1] = w.y;
        Ws[r][qd * 4 + 2] = w.z;
        Ws[r][qd * 4 + 3] = w.w;
    }
    __syncthreads();

    const int wave = tid >> 6, lane = tid & 63;
    const float bg1l = Bg1[lane];
    const float wg2l = Wg2[lane];
    const float b2   = Bg2[0];

    for (int rr = 0; rr < 4; ++rr) {
        const int row = blockIdx.x * 16 + wave * 4 + rr;
        float* orow = out + (size_t)row * DD;
        float s0 = 0.f, s1 = 0.f, s2 = 0.f, s3 = 0.f;
#pragma unroll 8
        for (int q = 0; q < 64; ++q) {
            float4 o = *(const float4*)(orow + q * 4);
            s0 += o.x * Ws[lane][q * 4 + 0];
            s1 += o.y * Ws[lane][q * 4 + 1];
            s2 += o.z * Ws[lane][q * 4 + 2];
            s3 += o.w * Ws[lane][q * 4 + 3];
        }
        float s = (s0 + s1) + (s2 + s3) + bg1l;
        float hh = s / (1.0f + __expf(-s));
        float t = hh * wg2l;
#pragma unroll
        for (int off = 32; off >= 1; off >>= 1) t += __shfl_xor(t, off, 64);
        const float gsc = 1.0f / (1.0f + __expf(-(t + b2)));

        float4 o = *(const float4*)(orow + lane * 4);
        o.x *= gsc; o.y *= gsc; o.z *= gsc; o.w *= gsc;
        *(float4*)(orow + lane * 4) = o;
    }
}

// ---------------------------------------------------------------------------
extern "C" void kernel_launch(void* const* d_in, const int* in_sizes, int n_in,
                              void* d_out, int out_size, void* d_ws, size_t ws_size,
                              hipStream_t stream) {
    (void)in_sizes; (void)n_in; (void)out_size; (void)ws_size;
    const float* x   = (const float*)d_in[0];
    const float* wq  = (const float*)d_in[1];
    const float* bq  = (const float*)d_in[2];
    const float* wk  = (const float*)d_in[3];
    const float* bk  = (const float*)d_in[4];
    const float* wv  = (const float*)d_in[5];
    const float* bv  = (const float*)d_in[6];
    const float* wg1 = (const float*)d_in[7];
    const float* bg1 = (const float*)d_in[8];
    const float* wg2 = (const float*)d_in[9];
    const float* bg2 = (const float*)d_in[10];
    float* out = (float*)d_out;

    const size_t NE = (size_t)BB * NN * DD;   // 1048576
    unsigned short* Qb  = (unsigned short*)d_ws;
    unsigned short* Kb  = Qb  + NE;
    unsigned short* Vb  = Kb  + NE;
    unsigned short* Xb  = Vb  + NE;
    unsigned short* Wqb = Xb  + NE;
    unsigned short* Wkb = Wqb + 65536;
    unsigned short* Wvb = Wkb + 65536;

    cvt_inputs<<<608, 256, 0, stream>>>(x, wq, wk, wv, Xb, Wqb, Wkb, Wvb);
    qkv_mfma<<<dim3(64, 4, 3), 256, 0, stream>>>(Xb, Wqb, Wkb, Wvb, bq, bk, bv,
                                                 Qb, Kb, Vb);
    attn_mfma<<<dim3(1024), 256, 0, stream>>>(Qb, Kb, Vb, out);
    gate_kernel<<<dim3(256), 256, 0, stream>>>(out, wg1, bg1, wg2, bg2);
}

// Round 6
// 61.361 us; speedup vs baseline: 9.1779x; 1.0597x over previous
//
#include <hip/hip_runtime.h>
#include <hip/hip_bf16.h>
#include <math.h>

#define BB 2
#define NN 2048
#define DD 256
#define HH 8

typedef __attribute__((ext_vector_type(8))) short bfrag8;
typedef __attribute__((ext_vector_type(4))) short bfrag4;
typedef __attribute__((ext_vector_type(4))) float f32x4;
typedef __attribute__((ext_vector_type(4))) unsigned short us4;
typedef __attribute__((ext_vector_type(8))) short s8v;

__device__ __forceinline__ unsigned short bf16rn(float f) {
    union { float f; unsigned u; } un; un.f = f;
    unsigned r = un.u + 0x7FFFu + ((un.u >> 16) & 1u);
    return (unsigned short)(r >> 16);
}

__device__ __forceinline__ f32x4 mfma16(bfrag4 a, bfrag4 b, f32x4 c) {
#if __has_builtin(__builtin_amdgcn_mfma_f32_16x16x16_bf16)
    return __builtin_amdgcn_mfma_f32_16x16x16_bf16(a, b, c, 0, 0, 0);
#else
    return __builtin_amdgcn_mfma_f32_16x16x16bf16_1k(a, b, c, 0, 0, 0);
#endif
}

// pair swizzle for the imag dot: {q0,q1,...} -> {q1,-q0,q3,-q2,...}
__device__ __forceinline__ bfrag8 pairswz(bfrag8 q) {
    union { bfrag8 f; unsigned u[4]; } a, r;
    a.f = q;
#pragma unroll
    for (int i = 0; i < 4; ++i) {
        unsigned d = a.u[i];
        r.u[i] = ((d >> 16) | (d << 16)) ^ 0x80000000u;
    }
    return r.f;
}

// w-chain: y = SC2 * re/|z|;  P = exp(y) via cubic Taylor (|y|<=0.0884);
// pack 4 probs to bf16 pairs with v_cvt_pk_bf16_f32.   (r3-verified version)
__device__ __forceinline__ bfrag4 expchain(f32x4 re, f32x4 im, float SC2) {
    float p[4];
#pragma unroll
    for (int r = 0; r < 4; ++r) {
        const float rr = re[r], ii = im[r];
        const float r2 = fmaf(rr, rr, fmaf(ii, ii, 1e-30f));
        const float y  = SC2 * rr * __builtin_amdgcn_rsqf(r2);
        const float a  = fmaf(y, 0.16666667f, 0.5f);
        const float bq = fmaf(y, a, 1.0f);
        p[r] = fmaf(y, bq, 1.0f);
    }
    unsigned lo, hi;
    asm("v_cvt_pk_bf16_f32 %0, %1, %2" : "=v"(lo) : "v"(p[0]), "v"(p[1]));
    asm("v_cvt_pk_bf16_f32 %0, %1, %2" : "=v"(hi) : "v"(p[2]), "v"(p[3]));
    union { unsigned u[2]; bfrag4 f; } pu;
    pu.u[0] = lo; pu.u[1] = hi;
    return pu.f;
}

// ---------------------------------------------------------------------------
// K0: convert X and Wq/Wk/Wv f32 -> bf16.  (r3-verified version)
// ---------------------------------------------------------------------------
__global__ __launch_bounds__(256) void cvt_inputs(
    const float* __restrict__ X,
    const float* __restrict__ Wq, const float* __restrict__ Wk, const float* __restrict__ Wv,
    unsigned short* __restrict__ Xb,
    unsigned short* __restrict__ Wqb, unsigned short* __restrict__ Wkb, unsigned short* __restrict__ Wvb)
{
    const int i = blockIdx.x * 256 + threadIdx.x;
    const float* src; unsigned short* dst; size_t off;
    if (i < 131072)      { src = X;  dst = Xb;  off = (size_t)i * 8; }
    else if (i < 139264) { src = Wq; dst = Wqb; off = (size_t)(i - 131072) * 8; }
    else if (i < 147456) { src = Wk; dst = Wkb; off = (size_t)(i - 139264) * 8; }
    else                 { src = Wv; dst = Wvb; off = (size_t)(i - 147456) * 8; }
    float4 a = *(const float4*)(src + off);
    float4 b = *(const float4*)(src + off + 4);
    us4 lo = { bf16rn(a.x), bf16rn(a.y), bf16rn(a.z), bf16rn(a.w) };
    us4 hi = { bf16rn(b.x), bf16rn(b.y), bf16rn(b.z), bf16rn(b.w) };
    *(us4*)(dst + off)     = lo;
    *(us4*)(dst + off + 4) = hi;
}

// ---------------------------------------------------------------------------
// K1: MFMA QKV GEMM (64x64 tile, XOR-swizzled LDS).  z=0:Q, 1:K, 2:V(tiled).
// (r3-verified version)
// ---------------------------------------------------------------------------
__global__ __launch_bounds__(256) void qkv_mfma(
    const unsigned short* __restrict__ Xb,
    const unsigned short* __restrict__ Wqb, const unsigned short* __restrict__ Wkb,
    const unsigned short* __restrict__ Wvb,
    const float* __restrict__ bq, const float* __restrict__ bk, const float* __restrict__ bv,
    unsigned short* __restrict__ Qb, unsigned short* __restrict__ Kb, unsigned short* __restrict__ Vb)
{
    const int tid  = threadIdx.x;
    const int z    = blockIdx.z;
    const unsigned short* Wm = (z == 0) ? Wqb : (z == 1) ? Wkb : Wvb;
    const float*          bm = (z == 0) ? bq  : (z == 1) ? bk  : bv;

    const int Mbase = blockIdx.x * 64;
    const int Nbase = blockIdx.y * 64;

    __shared__ unsigned short Xs[64 * 64];
    __shared__ unsigned short Ws[64 * 64];

    const int wave = tid >> 6, lane = tid & 63;
    const int c = lane & 15, g = lane >> 4;

    const int srow = tid >> 2;
    const int sq   = tid & 3;
    const int soff = ((srow * 128 + sq * 16) ^ ((srow & 7) << 4));
    const unsigned short* gx = Xb + (size_t)(Mbase + srow) * DD + sq * 8;
    const unsigned short* gw = Wm + (size_t)(Nbase + srow) * DD + sq * 8;

    const int xrow = 16 * wave + c;
    const int xoff = ((xrow * 128 + g * 16) ^ ((xrow & 7) << 4));
    int woff[4];
#pragma unroll
    for (int j = 0; j < 4; ++j) {
        const int wrow = 16 * j + c;
        woff[j] = ((wrow * 128 + g * 16) ^ ((wrow & 7) << 4));
    }

    f32x4 acc[4];
#pragma unroll
    for (int j = 0; j < 4; ++j) acc[j] = (f32x4){0.f, 0.f, 0.f, 0.f};

    for (int k0 = 0; k0 < DD; k0 += 32) {
        *(s8v*)((char*)Xs + soff) = *(const s8v*)(gx + k0);
        *(s8v*)((char*)Ws + soff) = *(const s8v*)(gw + k0);
        __syncthreads();
        const bfrag8 xf = *(const bfrag8*)((const char*)Xs + xoff);
#pragma unroll
        for (int j = 0; j < 4; ++j) {
            const bfrag8 wf = *(const bfrag8*)((const char*)Ws + woff[j]);
            acc[j] = __builtin_amdgcn_mfma_f32_16x16x32_bf16(wf, xf, acc[j], 0, 0, 0);
        }
        __syncthreads();
    }

    const int n = Mbase + xrow;
    const int bb = n >> 11, m = n & (NN - 1);
#pragma unroll
    for (int j = 0; j < 4; ++j) {
        const int col0 = Nbase + 16 * j + 4 * g;
        float4 bias = *(const float4*)(bm + col0);
        float v0 = acc[j][0] + bias.x;
        float v1 = acc[j][1] + bias.y;
        float v2 = acc[j][2] + bias.z;
        float v3 = acc[j][3] + bias.w;
        if (z == 2) {
            const int t = m >> 4, gg = (m >> 2) & 3, jj = m & 3;
            const int h2 = col0 >> 5, dt = (col0 >> 4) & 1, cc0 = col0 & 15;
            const size_t base = (size_t)(bb * 8 + h2) * 65536
                              + (size_t)t * 512 + (size_t)(dt * 4 + jj);
            Vb[base + (size_t)(16 * gg + cc0 + 0) * 8] = bf16rn(v0);
            Vb[base + (size_t)(16 * gg + cc0 + 1) * 8] = bf16rn(v1);
            Vb[base + (size_t)(16 * gg + cc0 + 2) * 8] = bf16rn(v2);
            Vb[base + (size_t)(16 * gg + cc0 + 3) * 8] = bf16rn(v3);
        } else {
            us4 pk = { bf16rn(v0), bf16rn(v1), bf16rn(v2), bf16rn(v3) };
            unsigned short* Ob = (z == 0) ? Qb : Kb;
            *(us4*)(Ob + (size_t)n * DD + col0) = pk;
        }
    }
}

// ---------------------------------------------------------------------------
// K2: MFMA phase attention (r3-verified body).  ONLY new line: bijective XCD
// swizzle so the 64 blocks sharing one (b,h)'s 256 KB K/V land on one XCD.
// ---------------------------------------------------------------------------
__global__ __launch_bounds__(256, 4) void attn_mfma(
    const unsigned short* __restrict__ Qb, const unsigned short* __restrict__ Kb,
    const unsigned short* __restrict__ Vb, float* __restrict__ outp)
{
    const int tid  = threadIdx.x;
    const int wave = tid >> 6, lane = tid & 63;
    const int g = lane >> 4, c = lane & 15;
    const int bid  = blockIdx.x;                    // 1024 = 8 * 128
    const int wgid = (bid & 7) * 128 + (bid >> 3);  // bijective XCD cluster
    const int bh = wgid >> 6, qt = wgid & 63;
    const int b = bh >> 3, h = bh & 7;

    const size_t qoff = (size_t)(b * NN + qt * 32 + c) * DD + h * 32 + 8 * g;
    const bfrag8 qf0  = *(const bfrag8*)(Qb + qoff);
    const bfrag8 qf1  = *(const bfrag8*)(Qb + qoff + 16 * DD);
    const bfrag8 qpf0 = pairswz(qf0);
    const bfrag8 qpf1 = pairswz(qf1);

    const unsigned short* kbase = Kb + (size_t)(b * NN + wave * 512 + c) * DD + h * 32 + 8 * g;
    const unsigned short* vbase = Vb + (size_t)bh * 65536 + (size_t)(wave * 32) * 512 + lane * 8;

    const f32x4 zero = {0.f, 0.f, 0.f, 0.f};
    f32x4 o00 = zero, o01 = zero, od0 = zero;
    f32x4 o10 = zero, o11 = zero, od1 = zero;
    const bfrag4 ones = { 0x3F80, 0x3F80, 0x3F80, 0x3F80 };
    const float SC2 = 0.5f / (sqrtf(32.0f) + 1e-6f);

    bfrag8 kf = *(const bfrag8*)kbase;
    bfrag8 vf = *(const bfrag8*)vbase;

    for (int tt = 0; tt < 32; ++tt) {
        const int nx = (tt + 1) & 31;
        const bfrag8 kf_n = *(const bfrag8*)(kbase + (size_t)nx * 16 * DD);
        const bfrag8 vf_n = *(const bfrag8*)(vbase + (size_t)nx * 512);

        f32x4 re0 = __builtin_amdgcn_mfma_f32_16x16x32_bf16(kf, qf0,  zero, 0, 0, 0);
        f32x4 im0 = __builtin_amdgcn_mfma_f32_16x16x32_bf16(kf, qpf0, zero, 0, 0, 0);
        f32x4 re1 = __builtin_amdgcn_mfma_f32_16x16x32_bf16(kf, qf1,  zero, 0, 0, 0);
        f32x4 im1 = __builtin_amdgcn_mfma_f32_16x16x32_bf16(kf, qpf1, zero, 0, 0, 0);

        const bfrag4 pf0 = expchain(re0, im0, SC2);
        const bfrag4 pf1 = expchain(re1, im1, SC2);

        union { bfrag8 v8; bfrag4 v4[2]; } vs; vs.v8 = vf;
        o00 = mfma16(pf0, vs.v4[0], o00);
        o01 = mfma16(pf0, vs.v4[1], o01);
        od0 = mfma16(pf0, ones,     od0);
        o10 = mfma16(pf1, vs.v4[0], o10);
        o11 = mfma16(pf1, vs.v4[1], o11);
        od1 = mfma16(pf1, ones,     od1);

        kf = kf_n; vf = vf_n;
    }

    __shared__ float cO[4][32][33];
    __shared__ float cD[4][32];
#pragma unroll
    for (int r = 0; r < 4; ++r) {
        cO[wave][4 * g + r][c]           = o00[r];
        cO[wave][4 * g + r][16 + c]      = o01[r];
        cO[wave][16 + 4 * g + r][c]      = o10[r];
        cO[wave][16 + 4 * g + r][16 + c] = o11[r];
    }
    if (c == 0) {
#pragma unroll
        for (int r = 0; r < 4; ++r) {
            cD[wave][4 * g + r]      = od0[r];
            cD[wave][16 + 4 * g + r] = od1[r];
        }
    }
    __syncthreads();

    const int q  = tid >> 3;
    const int dp = tid & 7;
    const float den  = (cD[0][q] + cD[1][q]) + (cD[2][q] + cD[3][q]);
    const float rden = 1.0f / den;
    float4 s;
    s.x = ((cO[0][q][4 * dp + 0] + cO[1][q][4 * dp + 0]) + (cO[2][q][4 * dp + 0] + cO[3][q][4 * dp + 0])) * rden;
    s.y = ((cO[0][q][4 * dp + 1] + cO[1][q][4 * dp + 1]) + (cO[2][q][4 * dp + 1] + cO[3][q][4 * dp + 1])) * rden;
    s.z = ((cO[0][q][4 * dp + 2] + cO[1][q][4 * dp + 2]) + (cO[2][q][4 * dp + 2] + cO[3][q][4 * dp + 2])) * rden;
    s.w = ((cO[0][q][4 * dp + 3] + cO[1][q][4 * dp + 3]) + (cO[2][q][4 * dp + 3] + cO[3][q][4 * dp + 3])) * rden;
    *(float4*)(outp + (size_t)(b * NN + qt * 32 + q) * DD + h * 32 + 4 * dp) = s;
}

// ---------------------------------------------------------------------------
// K3: gate MLP + in-place scale.  r3-verified LDS-staged structure; only
// change: 4 rows/block (1 per wave), grid 1024 -> better occupancy/TLP.
// ---------------------------------------------------------------------------
__global__ __launch_bounds__(256) void gate_kernel(
    float* __restrict__ out,
    const float* __restrict__ Wg1, const float* __restrict__ Bg1,
    const float* __restrict__ Wg2, const float* __restrict__ Bg2)
{
    __shared__ float Ws[64][257];
    const int tid = threadIdx.x;
#pragma unroll
    for (int pass = 0; pass < 16; ++pass) {
        const int i = pass * 256 + tid;          // float4 chunk id
        const int r = i >> 6, qd = i & 63;
        float4 w = *(const float4*)(Wg1 + r * DD + qd * 4);
        Ws[r][qd * 4 + 0] = w.x;
        Ws[r][qd * 4 + 1] = w.y;
        Ws[r][qd * 4 + 2] = w.z;
        Ws[r][qd * 4 + 3] = w.w;
    }
    __syncthreads();

    const int wave = tid >> 6, lane = tid & 63;
    const int row  = blockIdx.x * 4 + wave;      // 0..4095
    float* orow = out + (size_t)row * DD;

    float s0 = 0.f, s1 = 0.f, s2 = 0.f, s3 = 0.f;
#pragma unroll 8
    for (int q = 0; q < 64; ++q) {
        float4 o = *(const float4*)(orow + q * 4);
        s0 += o.x * Ws[lane][q * 4 + 0];
        s1 += o.y * Ws[lane][q * 4 + 1];
        s2 += o.z * Ws[lane][q * 4 + 2];
        s3 += o.w * Ws[lane][q * 4 + 3];
    }
    float s = (s0 + s1) + (s2 + s3) + Bg1[lane];
    float hh = s / (1.0f + __expf(-s));
    float t = hh * Wg2[lane];
#pragma unroll
    for (int off = 32; off >= 1; off >>= 1) t += __shfl_xor(t, off, 64);
    const float gsc = 1.0f / (1.0f + __expf(-(t + Bg2[0])));

    float4 o = *(const float4*)(orow + lane * 4);
    o.x *= gsc; o.y *= gsc; o.z *= gsc; o.w *= gsc;
    *(float4*)(orow + lane * 4) = o;
}

// ---------------------------------------------------------------------------
extern "C" void kernel_launch(void* const* d_in, const int* in_sizes, int n_in,
                              void* d_out, int out_size, void* d_ws, size_t ws_size,
                              hipStream_t stream) {
    (void)in_sizes; (void)n_in; (void)out_size; (void)ws_size;
    const float* x   = (const float*)d_in[0];
    const float* wq  = (const float*)d_in[1];
    const float* bq  = (const float*)d_in[2];
    const float* wk  = (const float*)d_in[3];
    const float* bk  = (const float*)d_in[4];
    const float* wv  = (const float*)d_in[5];
    const float* bv  = (const float*)d_in[6];
    const float* wg1 = (const float*)d_in[7];
    const float* bg1 = (const float*)d_in[8];
    const float* wg2 = (const float*)d_in[9];
    const float* bg2 = (const float*)d_in[10];
    float* out = (float*)d_out;

    const size_t NE = (size_t)BB * NN * DD;   // 1048576
    unsigned short* Qb  = (unsigned short*)d_ws;
    unsigned short* Kb  = Qb  + NE;
    unsigned short* Vb  = Kb  + NE;
    unsigned short* Xb  = Vb  + NE;
    unsigned short* Wqb = Xb  + NE;
    unsigned short* Wkb = Wqb + 65536;
    unsigned short* Wvb = Wkb + 65536;

    cvt_inputs<<<608, 256, 0, stream>>>(x, wq, wk, wv, Xb, Wqb, Wkb, Wvb);
    qkv_mfma<<<dim3(64, 4, 3), 256, 0, stream>>>(Xb, Wqb, Wkb, Wvb, bq, bk, bv,
                                                 Qb, Kb, Vb);
    attn_mfma<<<dim3(1024), 256, 0, stream>>>(Qb, Kb, Vb, out);
    gate_kernel<<<dim3(1024), 256, 0, stream>>>(out, wg1, bg1, wg2, bg2);
}

// Round 7
// 60.491 us; speedup vs baseline: 9.3099x; 1.0144x over previous
//
#include <hip/hip_runtime.h>
#include <hip/hip_bf16.h>
#include <math.h>

#define BB 2
#define NN 2048
#define DD 256
#define HH 8

typedef __attribute__((ext_vector_type(8))) short bfrag8;
typedef __attribute__((ext_vector_type(4))) short bfrag4;
typedef __attribute__((ext_vector_type(4))) float f32x4;
typedef __attribute__((ext_vector_type(4))) unsigned short us4;
typedef __attribute__((ext_vector_type(8))) short s8v;

__device__ __forceinline__ unsigned short bf16rn(float f) {
    union { float f; unsigned u; } un; un.f = f;
    unsigned r = un.u + 0x7FFFu + ((un.u >> 16) & 1u);
    return (unsigned short)(r >> 16);
}

__device__ __forceinline__ f32x4 mfma16(bfrag4 a, bfrag4 b, f32x4 c) {
#if __has_builtin(__builtin_amdgcn_mfma_f32_16x16x16_bf16)
    return __builtin_amdgcn_mfma_f32_16x16x16_bf16(a, b, c, 0, 0, 0);
#else
    return __builtin_amdgcn_mfma_f32_16x16x16bf16_1k(a, b, c, 0, 0, 0);
#endif
}

// pair swizzle for the imag dot: {q0,q1,...} -> {q1,-q0,q3,-q2,...}
__device__ __forceinline__ bfrag8 pairswz(bfrag8 q) {
    union { bfrag8 f; unsigned u[4]; } a, r;
    a.f = q;
#pragma unroll
    for (int i = 0; i < 4; ++i) {
        unsigned d = a.u[i];
        r.u[i] = ((d >> 16) | (d << 16)) ^ 0x80000000u;
    }
    return r.f;
}

// w-chain: y = SC2 * re/|z|;  P = exp(y) via cubic Taylor (|y|<=0.0884);
// pack 4 probs to bf16 pairs with v_cvt_pk_bf16_f32.   (r3/r6-verified)
__device__ __forceinline__ bfrag4 expchain(f32x4 re, f32x4 im, float SC2) {
    float p[4];
#pragma unroll
    for (int r = 0; r < 4; ++r) {
        const float rr = re[r], ii = im[r];
        const float r2 = fmaf(rr, rr, fmaf(ii, ii, 1e-30f));
        const float y  = SC2 * rr * __builtin_amdgcn_rsqf(r2);
        const float a  = fmaf(y, 0.16666667f, 0.5f);
        const float bq = fmaf(y, a, 1.0f);
        p[r] = fmaf(y, bq, 1.0f);
    }
    unsigned lo, hi;
    asm("v_cvt_pk_bf16_f32 %0, %1, %2" : "=v"(lo) : "v"(p[0]), "v"(p[1]));
    asm("v_cvt_pk_bf16_f32 %0, %1, %2" : "=v"(hi) : "v"(p[2]), "v"(p[3]));
    union { unsigned u[2]; bfrag4 f; } pu;
    pu.u[0] = lo; pu.u[1] = hi;
    return pu.f;
}

// ---------------------------------------------------------------------------
// K0: convert X and Wq/Wk/Wv f32 -> bf16.  (r6-verified, unchanged)
// ---------------------------------------------------------------------------
__global__ __launch_bounds__(256) void cvt_inputs(
    const float* __restrict__ X,
    const float* __restrict__ Wq, const float* __restrict__ Wk, const float* __restrict__ Wv,
    unsigned short* __restrict__ Xb,
    unsigned short* __restrict__ Wqb, unsigned short* __restrict__ Wkb, unsigned short* __restrict__ Wvb)
{
    const int i = blockIdx.x * 256 + threadIdx.x;
    const float* src; unsigned short* dst; size_t off;
    if (i < 131072)      { src = X;  dst = Xb;  off = (size_t)i * 8; }
    else if (i < 139264) { src = Wq; dst = Wqb; off = (size_t)(i - 131072) * 8; }
    else if (i < 147456) { src = Wk; dst = Wkb; off = (size_t)(i - 139264) * 8; }
    else                 { src = Wv; dst = Wvb; off = (size_t)(i - 147456) * 8; }
    float4 a = *(const float4*)(src + off);
    float4 b = *(const float4*)(src + off + 4);
    us4 lo = { bf16rn(a.x), bf16rn(a.y), bf16rn(a.z), bf16rn(a.w) };
    us4 hi = { bf16rn(b.x), bf16rn(b.y), bf16rn(b.z), bf16rn(b.w) };
    *(us4*)(dst + off)     = lo;
    *(us4*)(dst + off + 4) = hi;
}

// ---------------------------------------------------------------------------
// K1: MFMA QKV GEMM (64x64 tile, XOR-swizzled LDS).  (r6-verified, unchanged)
// ---------------------------------------------------------------------------
__global__ __launch_bounds__(256) void qkv_mfma(
    const unsigned short* __restrict__ Xb,
    const unsigned short* __restrict__ Wqb, const unsigned short* __restrict__ Wkb,
    const unsigned short* __restrict__ Wvb,
    const float* __restrict__ bq, const float* __restrict__ bk, const float* __restrict__ bv,
    unsigned short* __restrict__ Qb, unsigned short* __restrict__ Kb, unsigned short* __restrict__ Vb)
{
    const int tid  = threadIdx.x;
    const int z    = blockIdx.z;
    const unsigned short* Wm = (z == 0) ? Wqb : (z == 1) ? Wkb : Wvb;
    const float*          bm = (z == 0) ? bq  : (z == 1) ? bk  : bv;

    const int Mbase = blockIdx.x * 64;
    const int Nbase = blockIdx.y * 64;

    __shared__ unsigned short Xs[64 * 64];
    __shared__ unsigned short Ws[64 * 64];

    const int wave = tid >> 6, lane = tid & 63;
    const int c = lane & 15, g = lane >> 4;

    const int srow = tid >> 2;
    const int sq   = tid & 3;
    const int soff = ((srow * 128 + sq * 16) ^ ((srow & 7) << 4));
    const unsigned short* gx = Xb + (size_t)(Mbase + srow) * DD + sq * 8;
    const unsigned short* gw = Wm + (size_t)(Nbase + srow) * DD + sq * 8;

    const int xrow = 16 * wave + c;
    const int xoff = ((xrow * 128 + g * 16) ^ ((xrow & 7) << 4));
    int woff[4];
#pragma unroll
    for (int j = 0; j < 4; ++j) {
        const int wrow = 16 * j + c;
        woff[j] = ((wrow * 128 + g * 16) ^ ((wrow & 7) << 4));
    }

    f32x4 acc[4];
#pragma unroll
    for (int j = 0; j < 4; ++j) acc[j] = (f32x4){0.f, 0.f, 0.f, 0.f};

    for (int k0 = 0; k0 < DD; k0 += 32) {
        *(s8v*)((char*)Xs + soff) = *(const s8v*)(gx + k0);
        *(s8v*)((char*)Ws + soff) = *(const s8v*)(gw + k0);
        __syncthreads();
        const bfrag8 xf = *(const bfrag8*)((const char*)Xs + xoff);
#pragma unroll
        for (int j = 0; j < 4; ++j) {
            const bfrag8 wf = *(const bfrag8*)((const char*)Ws + woff[j]);
            acc[j] = __builtin_amdgcn_mfma_f32_16x16x32_bf16(wf, xf, acc[j], 0, 0, 0);
        }
        __syncthreads();
    }

    const int n = Mbase + xrow;
    const int bb = n >> 11, m = n & (NN - 1);
#pragma unroll
    for (int j = 0; j < 4; ++j) {
        const int col0 = Nbase + 16 * j + 4 * g;
        float4 bias = *(const float4*)(bm + col0);
        float v0 = acc[j][0] + bias.x;
        float v1 = acc[j][1] + bias.y;
        float v2 = acc[j][2] + bias.z;
        float v3 = acc[j][3] + bias.w;
        if (z == 2) {
            const int t = m >> 4, gg = (m >> 2) & 3, jj = m & 3;
            const int h2 = col0 >> 5, dt = (col0 >> 4) & 1, cc0 = col0 & 15;
            const size_t base = (size_t)(bb * 8 + h2) * 65536
                              + (size_t)t * 512 + (size_t)(dt * 4 + jj);
            Vb[base + (size_t)(16 * gg + cc0 + 0) * 8] = bf16rn(v0);
            Vb[base + (size_t)(16 * gg + cc0 + 1) * 8] = bf16rn(v1);
            Vb[base + (size_t)(16 * gg + cc0 + 2) * 8] = bf16rn(v2);
            Vb[base + (size_t)(16 * gg + cc0 + 3) * 8] = bf16rn(v3);
        } else {
            us4 pk = { bf16rn(v0), bf16rn(v1), bf16rn(v2), bf16rn(v3) };
            unsigned short* Ob = (z == 0) ? Qb : Kb;
            *(us4*)(Ob + (size_t)n * DD + col0) = pk;
        }
    }
}

// ---------------------------------------------------------------------------
// K2: MFMA phase attention, SOFTWARE-PIPELINED.
// Per iter tt: load tile tt+2 | mfma32 for tile tt+1 | expchain+PV for tile tt.
// No stage depends on a same-iteration producer -> MFMA/VALU latencies hidden.
// Tail overrun (tiles 32/33) reads in-bounds ws garbage, computed-then-
// discarded (finite bf16; results never consumed).
// ---------------------------------------------------------------------------
__global__ __launch_bounds__(256, 4) void attn_mfma(
    const unsigned short* __restrict__ Qb, const unsigned short* __restrict__ Kb,
    const unsigned short* __restrict__ Vb, float* __restrict__ outp)
{
    const int tid  = threadIdx.x;
    const int wave = tid >> 6, lane = tid & 63;
    const int g = lane >> 4, c = lane & 15;
    const int bid  = blockIdx.x;                    // 1024 = 8 * 128
    const int wgid = (bid & 7) * 128 + (bid >> 3);  // bijective XCD cluster
    const int bh = wgid >> 6, qt = wgid & 63;
    const int b = bh >> 3, h = bh & 7;

    const size_t qoff = (size_t)(b * NN + qt * 32 + c) * DD + h * 32 + 8 * g;
    const bfrag8 qf0  = *(const bfrag8*)(Qb + qoff);
    const bfrag8 qf1  = *(const bfrag8*)(Qb + qoff + 16 * DD);
    const bfrag8 qpf0 = pairswz(qf0);
    const bfrag8 qpf1 = pairswz(qf1);

    const unsigned short* kbase = Kb + (size_t)(b * NN + wave * 512 + c) * DD + h * 32 + 8 * g;
    const unsigned short* vbase = Vb + (size_t)bh * 65536 + (size_t)(wave * 32) * 512 + lane * 8;

    const f32x4 zero = {0.f, 0.f, 0.f, 0.f};
    f32x4 o00 = zero, o01 = zero, od0 = zero;
    f32x4 o10 = zero, o11 = zero, od1 = zero;
    const bfrag4 ones = { 0x3F80, 0x3F80, 0x3F80, 0x3F80 };
    const float SC2 = 0.5f / (sqrtf(32.0f) + 1e-6f);

    // ---- pipeline prologue ----
    // tile 0 fragments + its re/im; tile 1 fragments in flight
    bfrag8 kf_c = *(const bfrag8*)kbase;                       // K tile 0
    bfrag8 vf_c = *(const bfrag8*)vbase;                       // V tile 0
    bfrag8 kf_n = *(const bfrag8*)(kbase + (size_t)16 * DD);   // K tile 1
    bfrag8 vf_n = *(const bfrag8*)(vbase + 512);               // V tile 1

    f32x4 reA0 = __builtin_amdgcn_mfma_f32_16x16x32_bf16(kf_c, qf0,  zero, 0, 0, 0);
    f32x4 imA0 = __builtin_amdgcn_mfma_f32_16x16x32_bf16(kf_c, qpf0, zero, 0, 0, 0);
    f32x4 reA1 = __builtin_amdgcn_mfma_f32_16x16x32_bf16(kf_c, qf1,  zero, 0, 0, 0);
    f32x4 imA1 = __builtin_amdgcn_mfma_f32_16x16x32_bf16(kf_c, qpf1, zero, 0, 0, 0);

#pragma unroll 2
    for (int tt = 0; tt < 32; ++tt) {
        // loads for tile tt+2 (garbage-but-safe at 32,33)
        const bfrag8 kf_2 = *(const bfrag8*)(kbase + (size_t)(tt + 2) * 16 * DD);
        const bfrag8 vf_2 = *(const bfrag8*)(vbase + (size_t)(tt + 2) * 512);

        // score MFMAs for tile tt+1
        const f32x4 reB0 = __builtin_amdgcn_mfma_f32_16x16x32_bf16(kf_n, qf0,  zero, 0, 0, 0);
        const f32x4 imB0 = __builtin_amdgcn_mfma_f32_16x16x32_bf16(kf_n, qpf0, zero, 0, 0, 0);
        const f32x4 reB1 = __builtin_amdgcn_mfma_f32_16x16x32_bf16(kf_n, qf1,  zero, 0, 0, 0);
        const f32x4 imB1 = __builtin_amdgcn_mfma_f32_16x16x32_bf16(kf_n, qpf1, zero, 0, 0, 0);

        // softmax weights + PV for tile tt (uses last iter's re/im)
        const bfrag4 pf0 = expchain(reA0, imA0, SC2);
        const bfrag4 pf1 = expchain(reA1, imA1, SC2);

        union { bfrag8 v8; bfrag4 v4[2]; } vs; vs.v8 = vf_c;
        o00 = mfma16(pf0, vs.v4[0], o00);
        o01 = mfma16(pf0, vs.v4[1], o01);
        od0 = mfma16(pf0, ones,     od0);
        o10 = mfma16(pf1, vs.v4[0], o10);
        o11 = mfma16(pf1, vs.v4[1], o11);
        od1 = mfma16(pf1, ones,     od1);

        // rotate pipeline registers
        reA0 = reB0; imA0 = imB0; reA1 = reB1; imA1 = imB1;
        kf_n = kf_2; vf_c = vf_n; vf_n = vf_2;
    }

    __shared__ float cO[4][32][33];
    __shared__ float cD[4][32];
#pragma unroll
    for (int r = 0; r < 4; ++r) {
        cO[wave][4 * g + r][c]           = o00[r];
        cO[wave][4 * g + r][16 + c]      = o01[r];
        cO[wave][16 + 4 * g + r][c]      = o10[r];
        cO[wave][16 + 4 * g + r][16 + c] = o11[r];
    }
    if (c == 0) {
#pragma unroll
        for (int r = 0; r < 4; ++r) {
            cD[wave][4 * g + r]      = od0[r];
            cD[wave][16 + 4 * g + r] = od1[r];
        }
    }
    __syncthreads();

    const int q  = tid >> 3;
    const int dp = tid & 7;
    const float den  = (cD[0][q] + cD[1][q]) + (cD[2][q] + cD[3][q]);
    const float rden = 1.0f / den;
    float4 s;
    s.x = ((cO[0][q][4 * dp + 0] + cO[1][q][4 * dp + 0]) + (cO[2][q][4 * dp + 0] + cO[3][q][4 * dp + 0])) * rden;
    s.y = ((cO[0][q][4 * dp + 1] + cO[1][q][4 * dp + 1]) + (cO[2][q][4 * dp + 1] + cO[3][q][4 * dp + 1])) * rden;
    s.z = ((cO[0][q][4 * dp + 2] + cO[1][q][4 * dp + 2]) + (cO[2][q][4 * dp + 2] + cO[3][q][4 * dp + 2])) * rden;
    s.w = ((cO[0][q][4 * dp + 3] + cO[1][q][4 * dp + 3]) + (cO[2][q][4 * dp + 3] + cO[3][q][4 * dp + 3])) * rden;
    *(float4*)(outp + (size_t)(b * NN + qt * 32 + q) * DD + h * 32 + 4 * dp) = s;
}

// ---------------------------------------------------------------------------
// K3: gate MLP + in-place scale.  (r6-verified, unchanged)
// ---------------------------------------------------------------------------
__global__ __launch_bounds__(256) void gate_kernel(
    float* __restrict__ out,
    const float* __restrict__ Wg1, const float* __restrict__ Bg1,
    const float* __restrict__ Wg2, const float* __restrict__ Bg2)
{
    __shared__ float Ws[64][257];
    const int tid = threadIdx.x;
#pragma unroll
    for (int pass = 0; pass < 16; ++pass) {
        const int i = pass * 256 + tid;          // float4 chunk id
        const int r = i >> 6, qd = i & 63;
        float4 w = *(const float4*)(Wg1 + r * DD + qd * 4);
        Ws[r][qd * 4 + 0] = w.x;
        Ws[r][qd * 4 + 1] = w.y;
        Ws[r][qd * 4 + 2] = w.z;
        Ws[r][qd * 4 + 3] = w.w;
    }
    __syncthreads();

    const int wave = tid >> 6, lane = tid & 63;
    const int row  = blockIdx.x * 4 + wave;      // 0..4095
    float* orow = out + (size_t)row * DD;

    float s0 = 0.f, s1 = 0.f, s2 = 0.f, s3 = 0.f;
#pragma unroll 8
    for (int q = 0; q < 64; ++q) {
        float4 o = *(const float4*)(orow + q * 4);
        s0 += o.x * Ws[lane][q * 4 + 0];
        s1 += o.y * Ws[lane][q * 4 + 1];
        s2 += o.z * Ws[lane][q * 4 + 2];
        s3 += o.w * Ws[lane][q * 4 + 3];
    }
    float s = (s0 + s1) + (s2 + s3) + Bg1[lane];
    float hh = s / (1.0f + __expf(-s));
    float t = hh * Wg2[lane];
#pragma unroll
    for (int off = 32; off >= 1; off >>= 1) t += __shfl_xor(t, off, 64);
    const float gsc = 1.0f / (1.0f + __expf(-(t + Bg2[0])));

    float4 o = *(const float4*)(orow + lane * 4);
    o.x *= gsc; o.y *= gsc; o.z *= gsc; o.w *= gsc;
    *(float4*)(orow + lane * 4) = o;
}

// ---------------------------------------------------------------------------
extern "C" void kernel_launch(void* const* d_in, const int* in_sizes, int n_in,
                              void* d_out, int out_size, void* d_ws, size_t ws_size,
                              hipStream_t stream) {
    (void)in_sizes; (void)n_in; (void)out_size; (void)ws_size;
    const float* x   = (const float*)d_in[0];
    const float* wq  = (const float*)d_in[1];
    const float* bq  = (const float*)d_in[2];
    const float* wk  = (const float*)d_in[3];
    const float* bk  = (const float*)d_in[4];
    const float* wv  = (const float*)d_in[5];
    const float* bv  = (const float*)d_in[6];
    const float* wg1 = (const float*)d_in[7];
    const float* bg1 = (const float*)d_in[8];
    const float* wg2 = (const float*)d_in[9];
    const float* bg2 = (const float*)d_in[10];
    float* out = (float*)d_out;

    const size_t NE = (size_t)BB * NN * DD;   // 1048576
    unsigned short* Qb  = (unsigned short*)d_ws;
    unsigned short* Kb  = Qb  + NE;
    unsigned short* Vb  = Kb  + NE;
    unsigned short* Xb  = Vb  + NE;
    unsigned short* Wqb = Xb  + NE;
    unsigned short* Wkb = Wqb + 65536;
    unsigned short* Wvb = Wkb + 65536;

    cvt_inputs<<<608, 256, 0, stream>>>(x, wq, wk, wv, Xb, Wqb, Wkb, Wvb);
    qkv_mfma<<<dim3(64, 4, 3), 256, 0, stream>>>(Xb, Wqb, Wkb, Wvb, bq, bk, bv,
                                                 Qb, Kb, Vb);
    attn_mfma<<<dim3(1024), 256, 0, stream>>>(Qb, Kb, Vb, out);
    gate_kernel<<<dim3(1024), 256, 0, stream>>>(out, wg1, bg1, wg2, bg2);
}